// Round 4
// baseline (257.888 us; speedup 1.0000x reference)
//
#include <hip/hip_runtime.h>
#include <math.h>

// EKF over 2048 independent trajectories, T=512 serial steps.
//
// R2 insight: Q, R, P0 diagonal + block-diagonal F + H selecting one coord
// per block => the 6-dim EKF decomposes EXACTLY into three independent
// 2-state/1-meas Kalman filters (x, y, theta).
//
// R3 insight: lane 3k+j = subsystem j of trajectory k (21 traj/wave).
//
// R4 fix: R2 and R3 both pinned at ~650 cy/step regardless of VALU count ->
// the loop was bound by the latency of the per-step z load (prefetch depth
// 1). This version keeps 8 loads in flight via an unrolled circular register
// buffer: consume zb[t&7], immediately issue load for t+8 into that slot.
// Effective load stall ~L/8 instead of ~L.

__device__ __forceinline__ float frcp(float x) { return __builtin_amdgcn_rcpf(x); }

// tanh(100*v) = 1 - 2/(exp(200*v)+1);  exp(200*v) = 2^(200*log2(e)*v)
__device__ __forceinline__ float tanh100(float v) {
    float e = exp2f(fminf(fmaxf(288.53900817779268f * v, -126.0f), 126.0f));
    return fmaf(-2.0f, frcp(e + 1.0f), 1.0f);
}

#define TRIPLES_PER_WAVE 21
#define PFD 8  // prefetch depth (T=512 is divisible by PFD)

__global__ __launch_bounds__(64) void ekf_kernel(
    const float* __restrict__ meas,        // (n_traj, T, 3)
    const float* __restrict__ init_state,  // (n_traj, 6)
    const float* __restrict__ dyna,        // (4,)
    const float* __restrict__ Qm,          // (6,6)
    const float* __restrict__ Rm,          // (3,3)
    const float* __restrict__ P0m,         // (6,6)
    float* __restrict__ out,               // (n_traj*T,)
    int n_traj, int T)
{
    const int lane = threadIdx.x;          // 0..63
    const int k    = lane / 3;             // triple index within wave
    const int j    = lane - 3 * k;         // subsystem: 0=x, 1=y, 2=theta
    const int traj = blockIdx.x * TRIPLES_PER_WAVE + k;

    const bool active = (k < TRIPLES_PER_WAVE) && (traj < n_traj);
    const int traj_eff = active ? traj : (n_traj - 1);

    const float DTc = 1.0f / 120.0f;
    const float fric = dyna[0];
    const float damp = dyna[1];

    // per-lane subsystem constants (theta block: linear -> ca=1, cf=0)
    const bool lin = (j == 2);
    const float ca_l  = lin ? 1.0f : (1.0f - DTc * damp);
    const float cf_l  = lin ? 0.0f : (DTc * fric);
    const float cb_l  = 100.0f * cf_l;
    const float ca2_l = ca_l - cb_l;       // a = ca2 + cb*t^2

    const int pi = (j == 0) ? 0 : (j == 1) ? 1 : 4;   // position state index
    const int vi = pi + 2;                            // velocity state index

    const float qp = Qm[pi * 7];
    const float qv = Qm[vi * 7];
    const float qc = Qm[pi * 6 + vi];
    const float r  = Rm[j * 4];

    float p00 = P0m[pi * 7];
    float p02 = P0m[pi * 6 + vi];
    float p22 = P0m[vi * 7];

    float pos = init_state[traj_eff * 6 + pi];
    float vel = init_state[traj_eff * 6 + vi];

    const float* __restrict__ zp = meas + (size_t)traj_eff * (size_t)T * 3u + j;
    float*       __restrict__ op = out  + (size_t)traj_eff * (size_t)T;
    const bool store_ok = active && (j == 0);

    // ---- deep prefetch pipeline: PFD loads in flight ----
    float zb[PFD];
    #pragma unroll
    for (int i = 0; i < PFD; ++i) zb[i] = zp[3 * i];

    #pragma unroll PFD
    for (int t = 0; t < T; ++t) {
        const float z = zb[t & (PFD - 1)];
        // issue replacement load for step t+PFD (clamped; surplus never used)
        {
            int tn = t + PFD;
            tn = (tn < T) ? tn : (T - 1);
            zb[t & (PFD - 1)] = zp[3 * tn];
        }

        // ---- predict ----
        const float tx   = tanh100(vel);
        const float u    = fmaf(DTc, p22, p02);
        const float pp00 = fmaf(DTc, p02 + u, p00) + qp;
        const float a    = fmaf(cb_l, tx * tx, ca2_l);
        const float pp02 = fmaf(a, u, qc);
        const float pp22 = fmaf(a * p22, a, qv);

        const float sp = fmaf(DTc, vel, pos);
        const float sv = fmaf(-cf_l, tx, ca_l * vel);

        // ---- update ----
        const float S  = pp00 + r;
        const float rs = frcp(S);
        const float yv = z - sp;
        const float K0 = pp00 * rs;
        const float K1 = pp02 * rs;
        pos = fmaf(K0, yv, sp);
        vel = fmaf(K1, yv, sv);
        const float g = r * rs;
        p00 = pp00 * g;
        p02 = pp02 * g;
        p22 = fmaf(-K1, pp02, pp22);

        // ---- loss combine across lane triple (feeds only the store) ----
        const float m  = (yv * yv) * rs;
        const float S1 = __shfl(S, lane + 1);
        const float S2 = __shfl(S, lane + 2);
        const float m1 = __shfl(m, lane + 1);
        const float m2 = __shfl(m, lane + 2);
        const float loss = (S * S1) * S2 + (m + m1 + m2);
        if (store_ok) op[t] = loss;
    }
}

extern "C" void kernel_launch(void* const* d_in, const int* in_sizes, int n_in,
                              void* d_out, int out_size, void* d_ws, size_t ws_size,
                              hipStream_t stream) {
    const float* meas = (const float*)d_in[0];
    const float* init_state = (const float*)d_in[1];
    const float* dyna = (const float*)d_in[2];
    const float* Qm  = (const float*)d_in[3];
    const float* Rm  = (const float*)d_in[4];
    const float* P0m = (const float*)d_in[5];
    float* out = (float*)d_out;

    const int n_traj = in_sizes[1] / 6;
    const int T = in_sizes[0] / (n_traj * 3);

    const int grid = (n_traj + TRIPLES_PER_WAVE - 1) / TRIPLES_PER_WAVE;
    ekf_kernel<<<grid, 64, 0, stream>>>(meas, init_state, dyna, Qm, Rm, P0m,
                                        out, n_traj, T);
}

// Round 5
// 144.213 us; speedup vs baseline: 1.7882x; 1.7882x over previous
//
#include <hip/hip_runtime.h>
#include <math.h>

// EKF over 2048 trajectories, T=512 serial steps; 3 lanes per trajectory
// (lane 3k+j = subsystem j of trajectory k; 21 traj/wave), decomposed into
// three independent 2-state/1-meas Kalman filters (R2/R3 insight).
//
// R5: the R2/R3 ~650 cy/step floor was the memory pipe: depth-1 prefetch on
// scattered per-step loads (21 lines/load, traj stride 6 KB) + scattered
// per-step stores (21 lines/store). Fix: 32-step time tiles staged via LDS.
//   - 8 coalesced float4 global loads per tile into registers, issued a
//     full tile ahead (latency hidden under ~2500 cy of compute)
//   - 8 ds_write_b128 into padded LDS (stride 100), per-step ds_read_b32
//     with depth-2 software prefetch (fully literal-unrolled 32-step loop)
//   - losses staged in LDS (stride 36), flushed as 3 coalesced dwordx4
//     stores per tile.  126+42 lines/tile vs 672+672 before.

#define TRIPLES 21
#define TILE    32
#define ZS      100              // zbuf row stride (floats); bank phase 4k
#define ZBUFSZ  (TRIPLES * ZS)   // 2100
#define OS      36               // obuf row stride (floats)
#define CHUNKS_Z 504             // 21*96/4 float4 chunks per z-tile
#define CHUNKS_O 168             // 21*32/4 float4 chunks per out-tile

__device__ __forceinline__ float frcp(float x) { return __builtin_amdgcn_rcpf(x); }

// tanh(100*v) = 1 - 2/(exp(200*v)+1)
__device__ __forceinline__ float tanh100(float v) {
    float e = exp2f(fminf(fmaxf(288.53900817779268f * v, -126.0f), 126.0f));
    return fmaf(-2.0f, frcp(e + 1.0f), 1.0f);
}

__global__ __launch_bounds__(64) void ekf_kernel(
    const float* __restrict__ meas,        // (n_traj, T, 3)
    const float* __restrict__ init_state,  // (n_traj, 6)
    const float* __restrict__ dyna,        // (4,)
    const float* __restrict__ Qm,          // (6,6)
    const float* __restrict__ Rm,          // (3,3)
    const float* __restrict__ P0m,         // (6,6)
    float* __restrict__ out,               // (n_traj*T,)
    int n_traj, int T)
{
    __shared__ float zbuf[2 * ZBUFSZ];
    __shared__ float obuf[TRIPLES * OS];

    const int lane  = threadIdx.x;         // 0..63
    const int k     = lane / 3;            // triple index (21 = pad lane 63)
    const int j     = lane - 3 * k;        // subsystem 0=x,1=y,2=theta
    const int traj0 = blockIdx.x * TRIPLES;
    const int kk    = (k < TRIPLES) ? k : (TRIPLES - 1);
    const int traj  = traj0 + kk;
    const int traj_eff = (traj < n_traj) ? traj : (n_traj - 1);
    const bool store_ok = (k < TRIPLES) && (traj < n_traj) && (j == 0);

    const int NT = T / TILE;               // 16
    const int T3 = 3 * T;                  // floats per trajectory of meas

    // ---- filter constants (per-lane; theta block is linear: ca=1,cf=0) ----
    const float DTc  = 1.0f / 120.0f;
    const float fric = dyna[0], damp = dyna[1];
    const bool  lin  = (j == 2);
    const float ca_l  = lin ? 1.0f : (1.0f - DTc * damp);
    const float cf_l  = lin ? 0.0f : (DTc * fric);
    const float cb_l  = 100.0f * cf_l;
    const float ca2_l = ca_l - cb_l;
    const int pi = (j == 0) ? 0 : (j == 1) ? 1 : 4;
    const int vi = pi + 2;
    const float qp = Qm[pi * 7], qv = Qm[vi * 7], qc = Qm[pi * 6 + vi];
    const float r  = Rm[j * 4];
    float p00 = P0m[pi * 7], p02 = P0m[pi * 6 + vi], p22 = P0m[vi * 7];
    float pos = init_state[traj_eff * 6 + pi];
    float vel = init_state[traj_eff * 6 + vi];

    // ---- phase-A (z staging) address tables: chunk c -> (row k, chunk w) ----
    int gofs[8], lofs[8];
    #pragma unroll
    for (int rr = 0; rr < 8; ++rr) {
        int c = rr * 64 + lane;
        c = (c < CHUNKS_Z) ? c : (CHUNKS_Z - 1);     // clamped dup: benign
        int ck = c / 24;                              // 24 chunks per row
        int cw = c - 24 * ck;
        int tr = traj0 + ck; tr = (tr < n_traj) ? tr : (n_traj - 1);
        gofs[rr] = tr * T3 + 4 * cw;                  // float offset in meas
        lofs[rr] = ck * ZS + 4 * cw;                  // dword offset in zbuf
    }

    // ---- flush address tables: chunk c -> (row k, quad wq) ----
    int fld[3]; int fst[3]; bool fok[3];
    #pragma unroll
    for (int rr = 0; rr < 3; ++rr) {
        int c = rr * 64 + lane;
        bool v = (c < CHUNKS_O);
        c = v ? c : (CHUNKS_O - 1);
        int ck = c >> 3, cw = c & 7;
        fld[rr] = ck * OS + 4 * cw;                   // dword offset in obuf
        fst[rr] = (traj0 + ck) * T + 4 * cw;          // float offset in out
        fok[rr] = v && (traj0 + ck < n_traj);
    }

    // ---- prologue: loads for tile 0 in flight ----
    float4 g[8];
    #pragma unroll
    for (int rr = 0; rr < 8; ++rr)
        g[rr] = *(const float4*)(meas + (size_t)gofs[rr]);

    const int obase = kk * OS;
    int cur = 0;

    #pragma unroll 1
    for (int tile = 0; tile < NT; ++tile) {
        // ---- stage tile n's z into zbuf[cur] ----
        const int zo = cur * ZBUFSZ;
        #pragma unroll
        for (int rr = 0; rr < 8; ++rr)
            *(float4*)&zbuf[zo + lofs[rr]] = g[rr];

        // ---- issue global loads for tile n+1 (hidden under compute) ----
        const int ntile = (tile + 1 < NT) ? (tile + 1) : tile;
        const int nofs  = ntile * (TILE * 3);
        #pragma unroll
        for (int rr = 0; rr < 8; ++rr)
            g[rr] = *(const float4*)(meas + (size_t)(gofs[rr] + nofs));

        __syncthreads();   // zbuf writes visible; also orders obuf reuse

        // ---- compute 32 steps; z via depth-2 LDS prefetch ----
        const int zb = zo + kk * ZS + j;   // dword index of this lane's z(0)
        float zc = zbuf[zb];
        float zn = zbuf[zb + 3];
        #pragma unroll
        for (int tl = 0; tl < TILE; ++tl) {
            const float zf = (tl + 2 < TILE) ? zbuf[zb + 3 * (tl + 2)] : 0.0f;

            const float tx   = tanh100(vel);
            const float u    = fmaf(DTc, p22, p02);
            const float pp00 = fmaf(DTc, p02 + u, p00) + qp;
            const float a    = fmaf(cb_l, tx * tx, ca2_l);
            const float pp02 = fmaf(a, u, qc);
            const float pp22 = fmaf(a * p22, a, qv);
            const float sp   = fmaf(DTc, vel, pos);
            const float sv   = fmaf(-cf_l, tx, ca_l * vel);
            const float S    = pp00 + r;
            const float rs   = frcp(S);
            const float yv   = zc - sp;
            const float K0   = pp00 * rs;
            const float K1   = pp02 * rs;
            pos = fmaf(K0, yv, sp);
            vel = fmaf(K1, yv, sv);
            const float gg = r * rs;
            p00 = pp00 * gg;
            p02 = pp02 * gg;
            p22 = fmaf(-K1, pp02, pp22);

            const float m  = (yv * yv) * rs;
            const float S1 = __shfl(S, lane + 1);
            const float S2 = __shfl(S, lane + 2);
            const float m1 = __shfl(m, lane + 1);
            const float m2 = __shfl(m, lane + 2);
            const float loss = (S * S1) * S2 + (m + m1 + m2);
            if (store_ok) obuf[obase + tl] = loss;

            zc = zn; zn = zf;
        }

        __syncthreads();   // obuf writes visible to flush readers

        // ---- flush obuf -> out (coalesced dwordx4) ----
        const int tb = tile * TILE;
        #pragma unroll
        for (int rr = 0; rr < 3; ++rr) {
            const float4 v = *(const float4*)&obuf[fld[rr]];
            if (fok[rr]) *(float4*)(out + (size_t)(fst[rr] + tb)) = v;
        }

        cur ^= 1;
    }
}

extern "C" void kernel_launch(void* const* d_in, const int* in_sizes, int n_in,
                              void* d_out, int out_size, void* d_ws, size_t ws_size,
                              hipStream_t stream) {
    const float* meas = (const float*)d_in[0];
    const float* init_state = (const float*)d_in[1];
    const float* dyna = (const float*)d_in[2];
    const float* Qm  = (const float*)d_in[3];
    const float* Rm  = (const float*)d_in[4];
    const float* P0m = (const float*)d_in[5];
    float* out = (float*)d_out;

    const int n_traj = in_sizes[1] / 6;
    const int T = in_sizes[0] / (n_traj * 3);

    const int grid = (n_traj + TRIPLES - 1) / TRIPLES;
    ekf_kernel<<<grid, 64, 0, stream>>>(meas, init_state, dyna, Qm, Rm, P0m,
                                        out, n_traj, T);
}

// Round 6
// 130.422 us; speedup vs baseline: 1.9773x; 1.1057x over previous
//
#include <hip/hip_runtime.h>
#include <math.h>

// EKF over 2048 trajectories, T=512 serial steps; lane 3k+j = subsystem j of
// trajectory k (21 traj/wave), three independent 2-state/1-meas Kalman
// filters per trajectory (R2/R3 insight). 32-step time tiles staged via LDS
// (R5). R6: single-wave blocks need no __syncthreads -> replace barriers
// with `s_waitcnt lgkmcnt(0)` fences so the cross-tile global prefetch is
// never drained by the barrier's vmcnt(0); move the loss combine/store out
// of the step loop (per-step: 2 conflict-free ds_write_b32 of S,m; per-tile
// flush does the triple-combine + coalesced stores).

#define TRIPLES 21
#define TILE    32
#define ZS      100              // zbuf row stride (floats), 16B-aligned
#define ZBUFSZ  (TRIPLES * ZS)   // 2100
#define SMS     33               // sS/sM row stride (floats) -> conflict-free
#define CHUNKS_Z 504             // 21*96/4 float4 chunks per z-tile

__device__ __forceinline__ float frcp(float x) { return __builtin_amdgcn_rcpf(x); }

// All prior DS ops (LDS) complete; does NOT touch vmcnt -> global prefetch
// stays in flight. Valid only because blocks are exactly one wave.
__device__ __forceinline__ void lds_fence() {
    asm volatile("s_waitcnt lgkmcnt(0)" ::: "memory");
}

// tanh(100*v) = 1 - 2/(exp2(c*v)+1); overflow/underflow of exp2 round-trips
// correctly (inf -> rcp 0 -> 1;  0 -> rcp(1) -> -1), so no clamp needed.
__device__ __forceinline__ float tanh100(float v) {
    float e = exp2f(288.53900817779268f * v);
    return fmaf(-2.0f, frcp(e + 1.0f), 1.0f);
}

__global__ __launch_bounds__(64) void ekf_kernel(
    const float* __restrict__ meas,        // (n_traj, T, 3)
    const float* __restrict__ init_state,  // (n_traj, 6)
    const float* __restrict__ dyna,        // (4,)
    const float* __restrict__ Qm,          // (6,6)
    const float* __restrict__ Rm,          // (3,3)
    const float* __restrict__ P0m,         // (6,6)
    float* __restrict__ out,               // (n_traj*T,)
    int n_traj, int T)
{
    __shared__ float zbuf[2 * ZBUFSZ];
    __shared__ float sS[64 * SMS];
    __shared__ float sM[64 * SMS];

    const int lane  = threadIdx.x;         // 0..63
    const int k     = lane / 3;
    const int j     = lane - 3 * k;        // subsystem 0=x,1=y,2=theta
    const int traj0 = blockIdx.x * TRIPLES;
    const int kk    = (k < TRIPLES) ? k : (TRIPLES - 1);
    const int traj  = traj0 + kk;
    const int traj_eff = (traj < n_traj) ? traj : (n_traj - 1);

    const int NT = T / TILE;               // 16
    const int T3 = 3 * T;

    // ---- filter constants (theta block is linear: ca=1, cf=0) ----
    const float DTc  = 1.0f / 120.0f;
    const float fric = dyna[0], damp = dyna[1];
    const bool  lin  = (j == 2);
    const float ca_l  = lin ? 1.0f : (1.0f - DTc * damp);
    const float cf_l  = lin ? 0.0f : (DTc * fric);
    const float cb_l  = 100.0f * cf_l;
    const float ca2_l = ca_l - cb_l;
    const int pi = (j == 0) ? 0 : (j == 1) ? 1 : 4;
    const int vi = pi + 2;
    const float qp = Qm[pi * 7], qv = Qm[vi * 7], qc = Qm[pi * 6 + vi];
    const float r  = Rm[j * 4];
    float p00 = P0m[pi * 7], p02 = P0m[pi * 6 + vi], p22 = P0m[vi * 7];
    float pos = init_state[traj_eff * 6 + pi];
    float vel = init_state[traj_eff * 6 + vi];

    // ---- staging address tables: chunk c -> (row ck, chunk cw) ----
    int gofs[8], lofs[8];
    #pragma unroll
    for (int rr = 0; rr < 8; ++rr) {
        int c = rr * 64 + lane;
        c = (c < CHUNKS_Z) ? c : (CHUNKS_Z - 1);      // clamped dup: benign
        int ck = c / 24;                               // 24 float4 per row
        int cw = c - 24 * ck;
        int tr = traj0 + ck; tr = (tr < n_traj) ? tr : (n_traj - 1);
        gofs[rr] = tr * T3 + 4 * cw;
        lofs[rr] = ck * ZS + 4 * cw;
    }

    // ---- flush invariants: round r covers rows ck = 2r + (lane>>5) ----
    const int fhi  = lane >> 5;
    const int ftw  = lane & 31;
    const int fsm0 = 3 * fhi * SMS + ftw;              // sm dword base, r=0
    const int fob0 = (traj0 + fhi) * T + ftw;          // out float base, r=0

    // ---- prologue: tile 0 loads in flight ----
    float4 g[8];
    #pragma unroll
    for (int rr = 0; rr < 8; ++rr)
        g[rr] = *(const float4*)(meas + (size_t)gofs[rr]);

    int cur = 0;

    #pragma unroll 1
    for (int tile = 0; tile < NT; ++tile) {
        // ---- stage tile's z into zbuf[cur] (waits vmcnt on g only) ----
        const int zo = cur * ZBUFSZ;
        #pragma unroll
        for (int rr = 0; rr < 8; ++rr)
            *(float4*)&zbuf[zo + lofs[rr]] = g[rr];

        // ---- issue next tile's global loads (stay in flight: no barrier) --
        const int ntile = (tile + 1 < NT) ? (tile + 1) : tile;
        const int nofs  = ntile * (TILE * 3);
        #pragma unroll
        for (int rr = 0; rr < 8; ++rr)
            g[rr] = *(const float4*)(meas + (size_t)(gofs[rr] + nofs));

        lds_fence();   // zbuf visible; prior flush reads drained

        // ---- compute 32 steps ----
        const float* __restrict__ zr  = &zbuf[zo + kk * ZS + j];
        float* __restrict__ sSr = &sS[lane * SMS];
        float* __restrict__ sMr = &sM[lane * SMS];

        #pragma unroll
        for (int tl = 0; tl < TILE; ++tl) {
            const float z    = zr[3 * tl];
            const float tx   = tanh100(vel);
            const float u    = fmaf(DTc, p22, p02);
            const float pp00 = fmaf(DTc, p02 + u, p00) + qp;
            const float a    = fmaf(cb_l, tx * tx, ca2_l);
            const float pp02 = fmaf(a, u, qc);
            const float pp22 = fmaf(a * p22, a, qv);
            const float sp   = fmaf(DTc, vel, pos);
            const float sv   = fmaf(-cf_l, tx, ca_l * vel);
            const float S    = pp00 + r;
            const float rs   = frcp(S);
            const float yv   = z - sp;
            const float rsy  = rs * yv;
            pos = fmaf(pp00, rsy, sp);
            vel = fmaf(pp02, rsy, sv);
            const float gg = r * rs;
            const float K1 = pp02 * rs;
            p00 = pp00 * gg;
            p02 = pp02 * gg;
            p22 = fmaf(-K1, pp02, pp22);
            const float m = (yv * yv) * rs;
            sSr[tl] = S;
            sMr[tl] = m;
        }

        lds_fence();   // sS/sM visible

        // ---- flush: combine triples, coalesced stores (2 rows/round) ----
        const int tb = tile * TILE;
        #pragma unroll
        for (int rr = 0; rr < 11; ++rr) {
            const int ck = 2 * rr + fhi;
            const bool ok = (rr * 64 + lane < TRIPLES * TILE) &&
                            (traj0 + ck < n_traj);
            const int sa = fsm0 + rr * (6 * SMS);
            const float S0 = sS[sa], S1 = sS[sa + SMS], S2 = sS[sa + 2 * SMS];
            const float m0 = sM[sa], m1 = sM[sa + SMS], m2 = sM[sa + 2 * SMS];
            const float loss = (S0 * S1) * S2 + (m0 + m1 + m2);
            if (ok) out[(size_t)(fob0 + 2 * rr * T + tb)] = loss;
        }

        cur ^= 1;
    }
}

extern "C" void kernel_launch(void* const* d_in, const int* in_sizes, int n_in,
                              void* d_out, int out_size, void* d_ws, size_t ws_size,
                              hipStream_t stream) {
    const float* meas = (const float*)d_in[0];
    const float* init_state = (const float*)d_in[1];
    const float* dyna = (const float*)d_in[2];
    const float* Qm  = (const float*)d_in[3];
    const float* Rm  = (const float*)d_in[4];
    const float* P0m = (const float*)d_in[5];
    float* out = (float*)d_out;

    const int n_traj = in_sizes[1] / 6;
    const int T = in_sizes[0] / (n_traj * 3);

    const int grid = (n_traj + TRIPLES - 1) / TRIPLES;
    ekf_kernel<<<grid, 64, 0, stream>>>(meas, init_state, dyna, Qm, Rm, P0m,
                                        out, n_traj, T);
}

// Round 7
// 127.783 us; speedup vs baseline: 2.0182x; 1.0206x over previous
//
#include <hip/hip_runtime.h>
#include <math.h>

// EKF over 2048 trajectories, T=512 serial steps; lane 3k+j = subsystem j of
// trajectory k (21 traj/wave), three independent 2-state/1-meas Kalman
// filters per trajectory (R2/R3). 32-step tiles staged via LDS (R5), no
// barriers needed (single-wave blocks, R6).
//
// R7: per-step LDS reads were the residual stall (reads scheduled per-step,
// ~120cy LDS latency partially exposed every iteration). Now:
//   - all 32 z ds_read_b32 hoisted to tile start into registers (latency
//     paid once per tile, reads pipeline at throughput)
//   - (S,m) written as ONE ds_write_b64 per step (float2, stride 35 pairs)
//   - no explicit fences: same-wave DS ops execute in program order, so
//     write->read ordering through LDS is automatic.

#define TRIPLES 21
#define TILE    32
#define ZS      100              // zbuf row stride (floats), 16B-aligned
#define ZBUFSZ  (TRIPLES * ZS)   // 2100
#define SMS     35               // sSM row stride (float2) -> <=4-way banks
#define CHUNKS_Z 504             // 21*96/4 float4 chunks per z-tile

__device__ __forceinline__ float frcp(float x) { return __builtin_amdgcn_rcpf(x); }

// tanh(100*v) = 1 - 2/(exp2(c*v)+1); exp2 overflow/underflow round-trips
// correctly through rcp (inf->1, 0->-1), so no clamp.
__device__ __forceinline__ float tanh100(float v) {
    float e = exp2f(288.53900817779268f * v);
    return fmaf(-2.0f, frcp(e + 1.0f), 1.0f);
}

__global__ __launch_bounds__(64) void ekf_kernel(
    const float* __restrict__ meas,        // (n_traj, T, 3)
    const float* __restrict__ init_state,  // (n_traj, 6)
    const float* __restrict__ dyna,        // (4,)
    const float* __restrict__ Qm,          // (6,6)
    const float* __restrict__ Rm,          // (3,3)
    const float* __restrict__ P0m,         // (6,6)
    float* __restrict__ out,               // (n_traj*T,)
    int n_traj, int T)
{
    __shared__ float  zbuf[2 * ZBUFSZ];
    __shared__ float2 sSM[64 * SMS];

    const int lane  = threadIdx.x;         // 0..63
    const int k     = lane / 3;
    const int j     = lane - 3 * k;        // subsystem 0=x,1=y,2=theta
    const int traj0 = blockIdx.x * TRIPLES;
    const int kk    = (k < TRIPLES) ? k : (TRIPLES - 1);
    const int traj  = traj0 + kk;
    const int traj_eff = (traj < n_traj) ? traj : (n_traj - 1);

    const int NT = T / TILE;               // 16
    const int T3 = 3 * T;

    // ---- filter constants (theta block is linear: ca=1, cf=0) ----
    const float DTc  = 1.0f / 120.0f;
    const float fric = dyna[0], damp = dyna[1];
    const bool  lin  = (j == 2);
    const float ca_l  = lin ? 1.0f : (1.0f - DTc * damp);
    const float cf_l  = lin ? 0.0f : (DTc * fric);
    const float cb_l  = 100.0f * cf_l;
    const float ca2_l = ca_l - cb_l;
    const int pi = (j == 0) ? 0 : (j == 1) ? 1 : 4;
    const int vi = pi + 2;
    const float qp = Qm[pi * 7], qv = Qm[vi * 7], qc = Qm[pi * 6 + vi];
    const float r  = Rm[j * 4];
    float p00 = P0m[pi * 7], p02 = P0m[pi * 6 + vi], p22 = P0m[vi * 7];
    float pos = init_state[traj_eff * 6 + pi];
    float vel = init_state[traj_eff * 6 + vi];

    // ---- staging address tables: chunk c -> (row ck, chunk cw) ----
    int gofs[8], lofs[8];
    #pragma unroll
    for (int rr = 0; rr < 8; ++rr) {
        int c = rr * 64 + lane;
        c = (c < CHUNKS_Z) ? c : (CHUNKS_Z - 1);      // clamped dup: benign
        int ck = c / 24;                               // 24 float4 per row
        int cw = c - 24 * ck;
        int tr = traj0 + ck; tr = (tr < n_traj) ? tr : (n_traj - 1);
        gofs[rr] = tr * T3 + 4 * cw;
        lofs[rr] = ck * ZS + 4 * cw;
    }

    // ---- flush invariants: round rr covers rows ck = 2rr + (lane>>5) ----
    const int fhi  = lane >> 5;
    const int ftw  = lane & 31;
    const int fsm0 = 3 * fhi * SMS + ftw;              // float2 index, rr=0
    const int fob0 = (traj0 + fhi) * T + ftw;          // out float idx, rr=0

    // ---- prologue: tile 0 loads in flight ----
    float4 g[8];
    #pragma unroll
    for (int rr = 0; rr < 8; ++rr)
        g[rr] = *(const float4*)(meas + (size_t)gofs[rr]);

    int cur = 0;

    #pragma unroll 1
    for (int tile = 0; tile < NT; ++tile) {
        // ---- stage tile's z into zbuf[cur] (waits vmcnt on g only) ----
        const int zo = cur * ZBUFSZ;
        #pragma unroll
        for (int rr = 0; rr < 8; ++rr)
            *(float4*)&zbuf[zo + lofs[rr]] = g[rr];

        // ---- issue next tile's global loads (in flight across compute) ----
        const int ntile = (tile + 1 < NT) ? (tile + 1) : tile;
        const int nofs  = ntile * (TILE * 3);
        #pragma unroll
        for (int rr = 0; rr < 8; ++rr)
            g[rr] = *(const float4*)(meas + (size_t)(gofs[rr] + nofs));

        // ---- hoist ALL z reads for this tile into registers ----
        // (same-wave DS ops are in program order: reads after the staging
        //  writes above see the new data, no fence needed)
        const float* __restrict__ zr = &zbuf[zo + kk * ZS + j];
        float zv[TILE];
        #pragma unroll
        for (int tl = 0; tl < TILE; ++tl) zv[tl] = zr[3 * tl];

        // ---- compute 32 steps: pure VALU + 1 ds_write_b64 per step ----
        float2* __restrict__ smr = &sSM[lane * SMS];
        #pragma unroll
        for (int tl = 0; tl < TILE; ++tl) {
            const float z    = zv[tl];
            const float tx   = tanh100(vel);
            const float u    = fmaf(DTc, p22, p02);
            const float pp00 = fmaf(DTc, p02 + u, p00) + qp;
            const float a    = fmaf(cb_l, tx * tx, ca2_l);
            const float pp02 = fmaf(a, u, qc);
            const float pp22 = fmaf(a * p22, a, qv);
            const float sp   = fmaf(DTc, vel, pos);
            const float sv   = fmaf(-cf_l, tx, ca_l * vel);
            const float S    = pp00 + r;
            const float rs   = frcp(S);
            const float yv   = z - sp;
            const float rsy  = rs * yv;
            pos = fmaf(pp00, rsy, sp);
            vel = fmaf(pp02, rsy, sv);
            const float gg = r * rs;
            const float K1 = pp02 * rs;
            p00 = pp00 * gg;
            p02 = pp02 * gg;
            p22 = fmaf(-K1, pp02, pp22);
            const float m = (yv * yv) * rs;
            smr[tl] = make_float2(S, m);
        }

        // ---- flush: combine triples, coalesced stores (2 rows/round) ----
        // (in-order DS: these reads see the writes above; next tile's
        //  writes cannot pass these reads)
        const int tb = tile * TILE;
        #pragma unroll
        for (int rr = 0; rr < 11; ++rr) {
            const int ck = 2 * rr + fhi;
            const bool ok = (rr * 64 + lane < TRIPLES * TILE) &&
                            (traj0 + ck < n_traj);
            const int sa = fsm0 + rr * (6 * SMS);
            const float2 a0 = sSM[sa];
            const float2 a1 = sSM[sa + SMS];
            const float2 a2 = sSM[sa + 2 * SMS];
            const float loss = (a0.x * a1.x) * a2.x + (a0.y + a1.y + a2.y);
            if (ok) out[(size_t)(fob0 + 2 * rr * T + tb)] = loss;
        }

        cur ^= 1;
    }
}

extern "C" void kernel_launch(void* const* d_in, const int* in_sizes, int n_in,
                              void* d_out, int out_size, void* d_ws, size_t ws_size,
                              hipStream_t stream) {
    const float* meas = (const float*)d_in[0];
    const float* init_state = (const float*)d_in[1];
    const float* dyna = (const float*)d_in[2];
    const float* Qm  = (const float*)d_in[3];
    const float* Rm  = (const float*)d_in[4];
    const float* P0m = (const float*)d_in[5];
    float* out = (float*)d_out;

    const int n_traj = in_sizes[1] / 6;
    const int T = in_sizes[0] / (n_traj * 3);

    const int grid = (n_traj + TRIPLES - 1) / TRIPLES;
    ekf_kernel<<<grid, 64, 0, stream>>>(meas, init_state, dyna, Qm, Rm, P0m,
                                        out, n_traj, T);
}

// Round 8
// 127.722 us; speedup vs baseline: 2.0191x; 1.0005x over previous
//
#include <hip/hip_runtime.h>
#include <math.h>

// EKF over 2048 trajectories, T=512 serial steps; lane 3k+j = subsystem j of
// trajectory k (21 traj/wave), three independent 2-state/1-meas Kalman
// filters per trajectory (R2/R3). 32-step tiles staged via LDS (R5), no
// barriers (single-wave blocks, R6), z reads hoisted to registers (R7).
//
// R8: solo-wave issue cadence means every non-VALU op and stall in the step
// loop costs full latency. The last per-step LDS op (ds_write_b64 of (S,m))
// is moved out: S,m live in register arrays across the tile and are dumped
// to LDS in one pipelined burst after the 32-step loop. Inner loop is now
// PURE VALU (25 fp + 3 trans per step, zero memory ops).

#define TRIPLES 21
#define TILE    32
#define ZS      100              // zbuf row stride (floats), 16B-aligned
#define ZBUFSZ  (TRIPLES * ZS)   // 2100
#define SMS     35               // sSM row stride (float2)
#define CHUNKS_Z 504             // 21*96/4 float4 chunks per z-tile

__device__ __forceinline__ float frcp(float x) { return __builtin_amdgcn_rcpf(x); }

// tanh(100*v) = 1 - 2/(exp2(c*v)+1); exp2 overflow/underflow round-trips
// correctly through rcp (inf->1, 0->-1), so no clamp.
__device__ __forceinline__ float tanh100(float v) {
    float e = exp2f(288.53900817779268f * v);
    return fmaf(-2.0f, frcp(e + 1.0f), 1.0f);
}

__global__ __launch_bounds__(64, 1) void ekf_kernel(
    const float* __restrict__ meas,        // (n_traj, T, 3)
    const float* __restrict__ init_state,  // (n_traj, 6)
    const float* __restrict__ dyna,        // (4,)
    const float* __restrict__ Qm,          // (6,6)
    const float* __restrict__ Rm,          // (3,3)
    const float* __restrict__ P0m,         // (6,6)
    float* __restrict__ out,               // (n_traj*T,)
    int n_traj, int T)
{
    __shared__ float  zbuf[2 * ZBUFSZ];
    __shared__ float2 sSM[64 * SMS];

    const int lane  = threadIdx.x;         // 0..63
    const int k     = lane / 3;
    const int j     = lane - 3 * k;        // subsystem 0=x,1=y,2=theta
    const int traj0 = blockIdx.x * TRIPLES;
    const int kk    = (k < TRIPLES) ? k : (TRIPLES - 1);
    const int traj  = traj0 + kk;
    const int traj_eff = (traj < n_traj) ? traj : (n_traj - 1);

    const int NT = T / TILE;               // 16
    const int T3 = 3 * T;

    // ---- filter constants (theta block is linear: ca=1, cf=0) ----
    const float DTc  = 1.0f / 120.0f;
    const float fric = dyna[0], damp = dyna[1];
    const bool  lin  = (j == 2);
    const float ca_l  = lin ? 1.0f : (1.0f - DTc * damp);
    const float cf_l  = lin ? 0.0f : (DTc * fric);
    const float cb_l  = 100.0f * cf_l;
    const float ca2_l = ca_l - cb_l;
    const int pi = (j == 0) ? 0 : (j == 1) ? 1 : 4;
    const int vi = pi + 2;
    const float qp = Qm[pi * 7], qv = Qm[vi * 7], qc = Qm[pi * 6 + vi];
    const float r  = Rm[j * 4];
    float p00 = P0m[pi * 7], p02 = P0m[pi * 6 + vi], p22 = P0m[vi * 7];
    float pos = init_state[traj_eff * 6 + pi];
    float vel = init_state[traj_eff * 6 + vi];

    // ---- staging address tables: chunk c -> (row ck, chunk cw) ----
    int gofs[8], lofs[8];
    #pragma unroll
    for (int rr = 0; rr < 8; ++rr) {
        int c = rr * 64 + lane;
        c = (c < CHUNKS_Z) ? c : (CHUNKS_Z - 1);      // clamped dup: benign
        int ck = c / 24;                               // 24 float4 per row
        int cw = c - 24 * ck;
        int tr = traj0 + ck; tr = (tr < n_traj) ? tr : (n_traj - 1);
        gofs[rr] = tr * T3 + 4 * cw;
        lofs[rr] = ck * ZS + 4 * cw;
    }

    // ---- flush invariants: round rr covers rows ck = 2rr + (lane>>5) ----
    const int fhi  = lane >> 5;
    const int ftw  = lane & 31;
    const int fsm0 = 3 * fhi * SMS + ftw;              // float2 index, rr=0
    const int fob0 = (traj0 + fhi) * T + ftw;          // out float idx, rr=0

    // ---- prologue: tile 0 loads in flight ----
    float4 g[8];
    #pragma unroll
    for (int rr = 0; rr < 8; ++rr)
        g[rr] = *(const float4*)(meas + (size_t)gofs[rr]);

    int cur = 0;

    #pragma unroll 1
    for (int tile = 0; tile < NT; ++tile) {
        // ---- stage tile's z into zbuf[cur] (waits vmcnt on g only) ----
        const int zo = cur * ZBUFSZ;
        #pragma unroll
        for (int rr = 0; rr < 8; ++rr)
            *(float4*)&zbuf[zo + lofs[rr]] = g[rr];

        // ---- issue next tile's global loads (in flight across compute) ----
        const int ntile = (tile + 1 < NT) ? (tile + 1) : tile;
        const int nofs  = ntile * (TILE * 3);
        #pragma unroll
        for (int rr = 0; rr < 8; ++rr)
            g[rr] = *(const float4*)(meas + (size_t)(gofs[rr] + nofs));

        // ---- hoist ALL z reads for this tile into registers ----
        const float* __restrict__ zr = &zbuf[zo + kk * ZS + j];
        float zv[TILE];
        #pragma unroll
        for (int tl = 0; tl < TILE; ++tl) zv[tl] = zr[3 * tl];

        // ---- compute 32 steps: PURE VALU (S,m stay in registers) ----
        float Sv[TILE], Mv[TILE];
        #pragma unroll
        for (int tl = 0; tl < TILE; ++tl) {
            const float z    = zv[tl];
            const float tx   = tanh100(vel);
            const float u    = fmaf(DTc, p22, p02);
            const float pp00 = fmaf(DTc, p02 + u, p00) + qp;
            const float a    = fmaf(cb_l, tx * tx, ca2_l);
            const float pp02 = fmaf(a, u, qc);
            const float pp22 = fmaf(a * p22, a, qv);
            const float sp   = fmaf(DTc, vel, pos);
            const float sv   = fmaf(-cf_l, tx, ca_l * vel);
            const float S    = pp00 + r;
            const float rs   = frcp(S);
            const float yv   = z - sp;
            const float rsy  = rs * yv;
            pos = fmaf(pp00, rsy, sp);
            vel = fmaf(pp02, rsy, sv);
            const float gg = r * rs;
            const float K1 = pp02 * rs;
            p00 = pp00 * gg;
            p02 = pp02 * gg;
            p22 = fmaf(-K1, pp02, pp22);
            Sv[tl] = S;
            Mv[tl] = (yv * yv) * rs;
        }

        // ---- burst-write (S,m) pairs to LDS (pipelined, off chain) ----
        float2* __restrict__ smr = &sSM[lane * SMS];
        #pragma unroll
        for (int tl = 0; tl < TILE; ++tl)
            smr[tl] = make_float2(Sv[tl], Mv[tl]);

        // ---- flush: combine triples, coalesced stores (2 rows/round) ----
        const int tb = tile * TILE;
        #pragma unroll
        for (int rr = 0; rr < 11; ++rr) {
            const int ck = 2 * rr + fhi;
            const bool ok = (rr * 64 + lane < TRIPLES * TILE) &&
                            (traj0 + ck < n_traj);
            const int sa = fsm0 + rr * (6 * SMS);
            const float2 a0 = sSM[sa];
            const float2 a1 = sSM[sa + SMS];
            const float2 a2 = sSM[sa + 2 * SMS];
            const float loss = (a0.x * a1.x) * a2.x + (a0.y + a1.y + a2.y);
            if (ok) out[(size_t)(fob0 + 2 * rr * T + tb)] = loss;
        }

        cur ^= 1;
    }
}

extern "C" void kernel_launch(void* const* d_in, const int* in_sizes, int n_in,
                              void* d_out, int out_size, void* d_ws, size_t ws_size,
                              hipStream_t stream) {
    const float* meas = (const float*)d_in[0];
    const float* init_state = (const float*)d_in[1];
    const float* dyna = (const float*)d_in[2];
    const float* Qm  = (const float*)d_in[3];
    const float* Rm  = (const float*)d_in[4];
    const float* P0m = (const float*)d_in[5];
    float* out = (float*)d_out;

    const int n_traj = in_sizes[1] / 6;
    const int T = in_sizes[0] / (n_traj * 3);

    const int grid = (n_traj + TRIPLES - 1) / TRIPLES;
    ekf_kernel<<<grid, 64, 0, stream>>>(meas, init_state, dyna, Qm, Rm, P0m,
                                        out, n_traj, T);
}